// Round 14
// baseline (94.317 us; speedup 1.0000x reference)
//
#include <hip/hip_runtime.h>

#define BB 4
#define CCH 256
#define OCH 256
#define HH 64
#define WW 64
#define HWSZ 4096

typedef __bf16 bf16_t;
typedef bf16_t bf16x8 __attribute__((ext_vector_type(8)));
typedef bf16_t bf16x2_t __attribute__((ext_vector_type(2)));
typedef float f32x4 __attribute__((ext_vector_type(4)));

// RNE f32x2 -> packed bf16 (compiler emits v_cvt_pk_bf16_f32)
__device__ __forceinline__ unsigned int packbf(float a, float b) {
    bf16x2_t p;
    p.x = (__bf16)a;
    p.y = (__bf16)b;
    return __builtin_bit_cast(unsigned int, p);
}
__device__ __forceinline__ float blo(unsigned int u) { return __uint_as_float(u << 16); }
__device__ __forceinline__ float bhi(unsigned int u) { return __uint_as_float(u & 0xFFFF0000u); }

// ---------------------------------------------------------------------------
// Kernel prep (verified R12/R13): blocks [0,256): x -> xT bf16 transpose.
// blocks [256,...): w1F repack | w2F repack | P zero | out bias-prefill.
// ---------------------------------------------------------------------------
__global__ __launch_bounds__(256) void k_prep(const float* __restrict__ x,
                                              const float* __restrict__ w_off,
                                              const float* __restrict__ w_def,
                                              const float* __restrict__ b_def,
                                              ushort* __restrict__ xT,
                                              ushort* __restrict__ w1F,
                                              ushort* __restrict__ w2F,
                                              float* __restrict__ P,
                                              float* __restrict__ out) {
    int bid = blockIdx.x;
    if (bid < 256) {
        int b = bid >> 6;
        int h = bid & 63;
        int tid = threadIdx.x;
        int wv = tid >> 6;
        int lane = tid & 63;

        __shared__ unsigned int buf[64][130];

        const float* xp = x + ((size_t)b * CCH + wv * 64) * HWSZ + h * WW + lane;
#pragma unroll 8
        for (int i = 0; i < 32; ++i) {
            float a = xp[(size_t)(2 * i) * HWSZ];
            float c = xp[(size_t)(2 * i + 1) * HWSZ];
            buf[lane][wv * 32 + i] = packbf(a, c);
        }
        __syncthreads();

        ushort* dst = xT + ((size_t)(b * 64 + h) * 64) * 256;
#pragma unroll
        for (int r = 0; r < 16; ++r) {
            int idx = tid + r * 256;
            int w = idx >> 6;
            int q = idx & 63;
            uint2 v = *(const uint2*)&buf[w][2 * q];
            *(uint2*)(dst + (size_t)w * 256 + q * 4) = v;
        }
        return;
    }

    int i = (bid - 256) * 256 + threadIdx.x;
    if (i < 73728) {
        int j = i & 7;
        int o = (i >> 3) & 31;
        int cSub = (i >> 8) & 31;
        int k = i >> 13;
        float v = 0.0f;
        if (o < 27) v = w_off[((size_t)o * CCH + cSub * 8 + j) * 9 + k];
        w1F[i] = (ushort)(packbf(v, 0.f) & 0xFFFFu);
        return;
    }
    i -= 73728;
    if (i < 589824) {
        int j = i & 7;
        int o = (i >> 3) & 255;
        int cg = (i >> 11) & 31;
        int k = i >> 16;
        float v = w_def[(size_t)o * 2304 + (cg * 8 + j) * 9 + k];
        w2F[i] = (ushort)(packbf(v, 0.f) & 0xFFFFu);
        return;
    }
    i -= 589824;
    if (i < 110592) {
        ((float4*)P)[i] = make_float4(0.f, 0.f, 0.f, 0.f);
        return;
    }
    i -= 110592;
    if (i < 1048576) {
        float v = b_def[(i >> 10) & 255];
        ((float4*)out)[i] = make_float4(v, v, v, v);
    }
}

// ---------------------------------------------------------------------------
// Kernel 2 (verified R13): pred conv via MFMA, 32o x 128px tiles, 9 chunks.
// ---------------------------------------------------------------------------
__global__ __launch_bounds__(512) void k_pred4(const ushort* __restrict__ xT,
                                               const ushort* __restrict__ w1F,
                                               float* __restrict__ P) {
    int bid = blockIdx.x;
    int L = (bid & 7) * 64 + (bid >> 3);
    int cs = L & 3;
    int hg = (L >> 2) & 31;
    int b  = L >> 7;
    int tid = threadIdx.x;
    int lane = tid & 63;
    int wv   = tid >> 6;
    int l16  = lane & 15;
    int lq   = lane >> 4;
    int spx  = tid >> 3;
    int cl   = tid & 7;

    __shared__ ushort b_lds[2][8][8][16][8];   // 32KB

    const ushort* xTb = xT + (size_t)b * HWSZ * 256 + cs * 64 + cl * 8;
    const bf16x8* w1v = (const bf16x8*)w1F;

    f32x4 acc[2];
    acc[0] = (f32x4){0.f, 0.f, 0.f, 0.f};
    acc[1] = (f32x4){0.f, 0.f, 0.f, 0.f};

    auto stageLoad = [&](int k, int tpx) -> uint4 {
        int row = hg * 2 + (tpx >> 6);
        int col = tpx & 63;
        int ys = row + k / 3 - 1;
        int xs = col + k % 3 - 1;
        bool ok = (ys >= 0 && ys < HH && xs >= 0 && xs < WW);
        uint4 v = make_uint4(0u, 0u, 0u, 0u);
        if (ok) v = *(const uint4*)(xTb + (size_t)(ys * WW + xs) * 256);
        return v;
    };
    auto stageWrite = [&](uint4 v, int buf, int tpx) {
        *(uint4*)&b_lds[buf][cl][tpx >> 4][(tpx & 15) ^ cl][0] = v;
    };

    {
        uint4 v0 = stageLoad(0, spx);
        uint4 v1 = stageLoad(0, spx + 64);
        stageWrite(v0, 0, spx);
        stageWrite(v1, 0, spx + 64);
    }
    __syncthreads();

    for (int t = 0; t < 9; ++t) {
        int cur = t & 1;
        uint4 n0, n1;
        if (t < 8) {
            n0 = stageLoad(t + 1, spx);
            n1 = stageLoad(t + 1, spx + 64);
        }
        bf16x8 a00 = w1v[(size_t)(t * 32 + cs * 8 + 0 * 4 + lq) * 32 + 0 * 16 + l16];
        bf16x8 a01 = w1v[(size_t)(t * 32 + cs * 8 + 0 * 4 + lq) * 32 + 1 * 16 + l16];
        bf16x8 a10 = w1v[(size_t)(t * 32 + cs * 8 + 1 * 4 + lq) * 32 + 0 * 16 + l16];
        bf16x8 a11 = w1v[(size_t)(t * 32 + cs * 8 + 1 * 4 + lq) * 32 + 1 * 16 + l16];
        bf16x8 b0 = *(const bf16x8*)&b_lds[cur][0 * 4 + lq][wv][l16 ^ (0 * 4 + lq)][0];
        bf16x8 b1 = *(const bf16x8*)&b_lds[cur][1 * 4 + lq][wv][l16 ^ (1 * 4 + lq)][0];
        acc[0] = __builtin_amdgcn_mfma_f32_16x16x32_bf16(a00, b0, acc[0], 0, 0, 0);
        acc[1] = __builtin_amdgcn_mfma_f32_16x16x32_bf16(a01, b0, acc[1], 0, 0, 0);
        acc[0] = __builtin_amdgcn_mfma_f32_16x16x32_bf16(a10, b1, acc[0], 0, 0, 0);
        acc[1] = __builtin_amdgcn_mfma_f32_16x16x32_bf16(a11, b1, acc[1], 0, 0, 0);
        if (t < 8) {
            stageWrite(n0, cur ^ 1, spx);
            stageWrite(n1, cur ^ 1, spx + 64);
        }
        __syncthreads();
    }

    int prow = hg * 2 + (wv >> 2);
    int pcol = (wv & 3) * 16 + l16;
#pragma unroll
    for (int mf = 0; mf < 2; ++mf) {
#pragma unroll
        for (int r = 0; r < 4; ++r) {
            int o = mf * 16 + lq * 4 + r;
            if (o < 27) {
                atomicAdd(&P[((size_t)b * 27 + o) * HWSZ + prow * WW + pcol],
                          acc[mf][r]);
            }
        }
    }
}

// ---------------------------------------------------------------------------
// Kernel 3: deformable sampling + bf16 MFMA GEMM.
// cs-split x4 (R12's verified indexing: chunk t = tap t, 64 ch) under R9/R13's
// verified pipeline structure (paired-body loop, gbA/gbB + wgt snapshots,
// aA/aB ping-pong, combine-after-MFMA, __syncthreads). 9 chunks = 4 pairs +
// tail. grid = 1024 -> 4 blocks/CU at VGPR 64. XCD-swizzled (one b x 32 h/XCD).
// ---------------------------------------------------------------------------
__global__ __launch_bounds__(512, 4) void k_deform12(const ushort* __restrict__ xT,
                                                     const float* __restrict__ P,
                                                     const float* __restrict__ b_off,
                                                     const ushort* __restrict__ w2F,
                                                     float* __restrict__ out) {
    int bid = blockIdx.x;
    int L = (bid & 7) * 128 + (bid >> 3);      // 1024 = 8*128, bijective
    int cs = L & 3;                            // 64-channel quarter
    int h  = (L >> 2) & 63;
    int b  = L >> 8;
    int tid = threadIdx.x;
    int lane = tid & 63;
    int wv   = tid >> 6;          // 0..7 -> o block = wv*32
    int l16  = lane & 15;
    int lq   = lane >> 4;
    int px   = tid >> 3;          // 0..63
    int cl   = tid & 7;           // 8-channel slot within the 64

    __shared__ ushort b_lds[2][8][4][16][8];   // [buf][kg][nt][p^kg][j] 16KB

    const char* xTc = (const char*)xT + (size_t)b * HWSZ * 512 + cs * 128 + cl * 16;
    const bf16x8* w2b = (const bf16x8*)w2F + wv * 32 + l16;

    uint4* wdst0 = (uint4*)&b_lds[0][cl][px >> 4][(px & 15) ^ cl][0];
    uint4* wdst1 = (uint4*)&b_lds[1][cl][px >> 4][(px & 15) ^ cl][0];

    f32x4 acc[2][4];
#pragma unroll
    for (int mf = 0; mf < 2; ++mf)
#pragma unroll
        for (int nt = 0; nt < 4; ++nt) acc[mf][nt] = (f32x4){0.f, 0.f, 0.f, 0.f};

    const float* Pb = P + (size_t)b * 27 * HWSZ + h * WW + px;

    float pOy, pOx, pMr, bOy, bOx, bMr;
    float wgt[4];
    const char* aptr[4];

    auto loadP = [&](int k) {
        pOy = Pb[(size_t)(2 * k) * HWSZ];
        pOx = Pb[(size_t)(2 * k + 1) * HWSZ];
        pMr = Pb[(size_t)(18 + k) * HWSZ];
        bOy = b_off[2 * k];
        bOx = b_off[2 * k + 1];
        bMr = b_off[18 + k];
    };
    auto calcDesc = [&](int k) {
        float offy = pOy + bOy;
        float offx = pOx + bOx;
        float m = 1.0f / (1.0f + expf(-(pMr + bMr)));
        float sy = offy + (float)(h + k / 3 - 1);
        float sx = offx + (float)(px + k % 3 - 1);
        float y0f = floorf(sy), x0f = floorf(sx);
        float ty = sy - y0f, tx = sx - x0f;
        int y0 = (int)y0f, x0 = (int)x0f;
#pragma unroll
        for (int dy = 0; dy < 2; ++dy) {
#pragma unroll
            for (int dx = 0; dx < 2; ++dx) {
                int yi = y0 + dy, xi = x0 + dx;
                bool ok = (yi >= 0 && yi < HH && xi >= 0 && xi < WW);
                float wg = (dy ? ty : 1.0f - ty) * (dx ? tx : 1.0f - tx) * m;
                wgt[dy * 2 + dx]  = ok ? wg : 0.0f;
                aptr[dy * 2 + dx] = xTc + (size_t)(ok ? (yi * WW + xi) : 0) * 512;
            }
        }
    };

    // named pipeline slots (static indexing only — rule #20)
    uint4 gbA[4], gbB[4];
    float wgtA[4], wgtB[4];
    bf16x8 aA[2][2], aB[2][2];

    auto issueGatherTo = [&](uint4 (&gb)[4], float (&wg)[4]) {
#pragma unroll
        for (int c = 0; c < 4; ++c) gb[c] = *(const uint4*)(aptr[c]);
#pragma unroll
        for (int c = 0; c < 4; ++c) wg[c] = wgt[c];
    };
    auto combineFrom = [&](const uint4 (&g)[4], const float (&w)[4]) -> uint4 {
        uint4 r;
        {
            float lo = w[0]*blo(g[0].x) + w[1]*blo(g[1].x) + w[2]*blo(g[2].x) + w[3]*blo(g[3].x);
            float hi = w[0]*bhi(g[0].x) + w[1]*bhi(g[1].x) + w[2]*bhi(g[2].x) + w[3]*bhi(g[3].x);
            r.x = packbf(lo, hi);
        }
        {
            float lo = w[0]*blo(g[0].y) + w[1]*blo(g[1].y) + w[2]*blo(g[2].y) + w[3]*blo(g[3].y);
            float hi = w[0]*bhi(g[0].y) + w[1]*bhi(g[1].y) + w[2]*bhi(g[2].y) + w[3]*bhi(g[3].y);
            r.y = packbf(lo, hi);
        }
        {
            float lo = w[0]*blo(g[0].z) + w[1]*blo(g[1].z) + w[2]*blo(g[2].z) + w[3]*blo(g[3].z);
            float hi = w[0]*bhi(g[0].z) + w[1]*bhi(g[1].z) + w[2]*bhi(g[2].z) + w[3]*bhi(g[3].z);
            r.z = packbf(lo, hi);
        }
        {
            float lo = w[0]*blo(g[0].w) + w[1]*blo(g[1].w) + w[2]*blo(g[2].w) + w[3]*blo(g[3].w);
            float hi = w[0]*bhi(g[0].w) + w[1]*bhi(g[1].w) + w[2]*bhi(g[2].w) + w[3]*bhi(g[3].w);
            r.w = packbf(lo, hi);
        }
        return r;
    };
    // chunk t = tap t: A rows t*32 + cs*8 + g*4 + lq  (verified R12 indexing)
    auto loadATo = [&](bf16x8 (&a)[2][2], int t) {
        size_t base = ((size_t)(t * 32 + cs * 8) + lq) * 256;
#pragma unroll
        for (int g = 0; g < 2; ++g)
#pragma unroll
            for (int mf = 0; mf < 2; ++mf)
                a[mf][g] = w2b[base + (size_t)g * 1024 + mf * 16];
    };

#define MFMA_BODY(BUF, AREG)                                                        \
    do {                                                                            \
        bf16x8 bfr[2][4];                                                           \
        _Pragma("unroll")                                                           \
        for (int g = 0; g < 2; ++g) {                                               \
            int kg = g * 4 + lq;                                                    \
            _Pragma("unroll")                                                       \
            for (int nt = 0; nt < 4; ++nt)                                          \
                bfr[g][nt] = *(const bf16x8*)&b_lds[BUF][kg][nt][l16 ^ kg][0];      \
        }                                                                           \
        _Pragma("unroll")                                                           \
        for (int g = 0; g < 2; ++g)                                                 \
            _Pragma("unroll")                                                       \
            for (int mf = 0; mf < 2; ++mf)                                          \
                _Pragma("unroll")                                                   \
                for (int nt = 0; nt < 4; ++nt)                                      \
                    acc[mf][nt] = __builtin_amdgcn_mfma_f32_16x16x32_bf16(          \
                        AREG[mf][g], bfr[g][nt], acc[mf][nt], 0, 0, 0);             \
    } while (0)

    // --- prologue: chunk 0 -> gbA -> buf0; chunk 1 -> gbB; A chunk 0; P(0..2) ---
    loadP(0);
    calcDesc(0);
    issueGatherTo(gbA, wgtA);         // chunk 0
    loadP(1);
    calcDesc(1);
    issueGatherTo(gbB, wgtB);         // chunk 1
    loadP(2);
    loadATo(aA, 0);
    *wdst0 = combineFrom(gbA, wgtA);
    __syncthreads();

    for (int tp = 0; tp < 4; ++tp) {
        // ---- even body t=2tp: MFMA buf0/aA(chunk 2tp); combine gbB(2tp+1)->buf1 ----
        calcDesc(2 * tp + 2);
        issueGatherTo(gbA, wgtA);                 // chunk 2tp+2
        if (tp < 3) loadP(2 * tp + 3);
        loadATo(aB, 2 * tp + 1);
        MFMA_BODY(0, aA);
        *wdst1 = combineFrom(gbB, wgtB);          // chunk 2tp+1 -> buf1
        __syncthreads();

        // ---- odd body t=2tp+1: MFMA buf1/aB(chunk 2tp+1); combine gbA(2tp+2)->buf0 ----
        if (tp < 3) {
            calcDesc(2 * tp + 3);
            issueGatherTo(gbB, wgtB);             // chunk 2tp+3
            loadP(2 * tp + 4);
        }
        loadATo(aA, 2 * tp + 2);
        MFMA_BODY(1, aB);
        *wdst0 = combineFrom(gbA, wgtA);          // chunk 2tp+2 -> buf0
        __syncthreads();
    }
    // ---- tail body t=8: MFMA buf0/aA(chunk 8) ----
    MFMA_BODY(0, aA);
#undef MFMA_BODY

    // epilogue: atomic accumulate (out prefilled with bias)
#pragma unroll
    for (int mf = 0; mf < 2; ++mf) {
#pragma unroll
        for (int nt = 0; nt < 4; ++nt) {
#pragma unroll
            for (int r = 0; r < 4; ++r) {
                int o = wv * 32 + mf * 16 + lq * 4 + r;
                atomicAdd(&out[((size_t)b * OCH + o) * HWSZ + h * WW + nt * 16 + l16],
                          acc[mf][nt][r]);
            }
        }
    }
}

// ---------------------------------------------------------------------------
extern "C" void kernel_launch(void* const* d_in, const int* in_sizes, int n_in,
                              void* d_out, int out_size, void* d_ws, size_t ws_size,
                              hipStream_t stream) {
    const float* x     = (const float*)d_in[0];
    const float* w_off = (const float*)d_in[1];
    const float* b_off = (const float*)d_in[2];
    const float* w_def = (const float*)d_in[3];
    const float* b_def = (const float*)d_in[4];
    float* out = (float*)d_out;

    float*  P   = (float*)d_ws;                            // 442368 f32
    ushort* w1F = (ushort*)(P + (size_t)BB * 27 * HWSZ);   // 73728 bf16
    ushort* w2F = w1F + 73728;                             // 589824 bf16
    ushort* xT  = w2F + 589824;                            // 4.19M bf16

    hipLaunchKernelGGL(k_prep, dim3(7376), dim3(256), 0, stream,
                       x, w_off, w_def, b_def, xT, w1F, w2F, P, out);
    hipLaunchKernelGGL(k_pred4, dim3(512), dim3(512), 0, stream, xT, w1F, P);
    hipLaunchKernelGGL(k_deform12, dim3(1024), dim3(512), 0, stream, xT, P, b_off, w2F, out);
}

// Round 15
// 84.107 us; speedup vs baseline: 1.1214x; 1.1214x over previous
//
#include <hip/hip_runtime.h>

#define BB 4
#define CCH 256
#define OCH 256
#define HH 64
#define WW 64
#define HWSZ 4096

typedef __bf16 bf16_t;
typedef bf16_t bf16x8 __attribute__((ext_vector_type(8)));
typedef bf16_t bf16x2_t __attribute__((ext_vector_type(2)));
typedef float f32x4 __attribute__((ext_vector_type(4)));

// RNE f32x2 -> packed bf16 (compiler emits v_cvt_pk_bf16_f32)
__device__ __forceinline__ unsigned int packbf(float a, float b) {
    bf16x2_t p;
    p.x = (__bf16)a;
    p.y = (__bf16)b;
    return __builtin_bit_cast(unsigned int, p);
}
__device__ __forceinline__ float blo(unsigned int u) { return __uint_as_float(u << 16); }
__device__ __forceinline__ float bhi(unsigned int u) { return __uint_as_float(u & 0xFFFF0000u); }

// lgkm-only barrier: orders LDS traffic across the block WITHOUT draining the
// vmem queue (vs __syncthreads' s_waitcnt vmcnt(0)). In-flight register
// gathers survive the barrier; their consumers get compiler-emitted vmcnt(N).
// NO sched_barrier here (R10's regression came from freezing the scheduler).
__device__ __forceinline__ void lgkm_sync() {
    asm volatile("s_waitcnt lgkmcnt(0)" ::: "memory");
    __builtin_amdgcn_s_barrier();
}

// ---------------------------------------------------------------------------
// Kernel prep (verified R12/R13): blocks [0,256): x -> xT bf16 transpose.
// blocks [256,...): w1F repack | w2F repack | P zero | out bias-prefill.
// ---------------------------------------------------------------------------
__global__ __launch_bounds__(256) void k_prep(const float* __restrict__ x,
                                              const float* __restrict__ w_off,
                                              const float* __restrict__ w_def,
                                              const float* __restrict__ b_def,
                                              ushort* __restrict__ xT,
                                              ushort* __restrict__ w1F,
                                              ushort* __restrict__ w2F,
                                              float* __restrict__ P,
                                              float* __restrict__ out) {
    int bid = blockIdx.x;
    if (bid < 256) {
        int b = bid >> 6;
        int h = bid & 63;
        int tid = threadIdx.x;
        int wv = tid >> 6;
        int lane = tid & 63;

        __shared__ unsigned int buf[64][130];

        const float* xp = x + ((size_t)b * CCH + wv * 64) * HWSZ + h * WW + lane;
#pragma unroll 8
        for (int i = 0; i < 32; ++i) {
            float a = xp[(size_t)(2 * i) * HWSZ];
            float c = xp[(size_t)(2 * i + 1) * HWSZ];
            buf[lane][wv * 32 + i] = packbf(a, c);
        }
        __syncthreads();

        ushort* dst = xT + ((size_t)(b * 64 + h) * 64) * 256;
#pragma unroll
        for (int r = 0; r < 16; ++r) {
            int idx = tid + r * 256;
            int w = idx >> 6;
            int q = idx & 63;
            uint2 v = *(const uint2*)&buf[w][2 * q];
            *(uint2*)(dst + (size_t)w * 256 + q * 4) = v;
        }
        return;
    }

    int i = (bid - 256) * 256 + threadIdx.x;
    if (i < 73728) {
        int j = i & 7;
        int o = (i >> 3) & 31;
        int cSub = (i >> 8) & 31;
        int k = i >> 13;
        float v = 0.0f;
        if (o < 27) v = w_off[((size_t)o * CCH + cSub * 8 + j) * 9 + k];
        w1F[i] = (ushort)(packbf(v, 0.f) & 0xFFFFu);
        return;
    }
    i -= 73728;
    if (i < 589824) {
        int j = i & 7;
        int o = (i >> 3) & 255;
        int cg = (i >> 11) & 31;
        int k = i >> 16;
        float v = w_def[(size_t)o * 2304 + (cg * 8 + j) * 9 + k];
        w2F[i] = (ushort)(packbf(v, 0.f) & 0xFFFFu);
        return;
    }
    i -= 589824;
    if (i < 110592) {
        ((float4*)P)[i] = make_float4(0.f, 0.f, 0.f, 0.f);
        return;
    }
    i -= 110592;
    if (i < 1048576) {
        float v = b_def[(i >> 10) & 255];
        ((float4*)out)[i] = make_float4(v, v, v, v);
    }
}

// ---------------------------------------------------------------------------
// Kernel 2 (verified R13): pred conv via MFMA, 32o x 128px tiles, 9 chunks.
// ---------------------------------------------------------------------------
__global__ __launch_bounds__(512) void k_pred4(const ushort* __restrict__ xT,
                                               const ushort* __restrict__ w1F,
                                               float* __restrict__ P) {
    int bid = blockIdx.x;
    int L = (bid & 7) * 64 + (bid >> 3);
    int cs = L & 3;
    int hg = (L >> 2) & 31;
    int b  = L >> 7;
    int tid = threadIdx.x;
    int lane = tid & 63;
    int wv   = tid >> 6;
    int l16  = lane & 15;
    int lq   = lane >> 4;
    int spx  = tid >> 3;
    int cl   = tid & 7;

    __shared__ ushort b_lds[2][8][8][16][8];   // 32KB

    const ushort* xTb = xT + (size_t)b * HWSZ * 256 + cs * 64 + cl * 8;
    const bf16x8* w1v = (const bf16x8*)w1F;

    f32x4 acc[2];
    acc[0] = (f32x4){0.f, 0.f, 0.f, 0.f};
    acc[1] = (f32x4){0.f, 0.f, 0.f, 0.f};

    auto stageLoad = [&](int k, int tpx) -> uint4 {
        int row = hg * 2 + (tpx >> 6);
        int col = tpx & 63;
        int ys = row + k / 3 - 1;
        int xs = col + k % 3 - 1;
        bool ok = (ys >= 0 && ys < HH && xs >= 0 && xs < WW);
        uint4 v = make_uint4(0u, 0u, 0u, 0u);
        if (ok) v = *(const uint4*)(xTb + (size_t)(ys * WW + xs) * 256);
        return v;
    };
    auto stageWrite = [&](uint4 v, int buf, int tpx) {
        *(uint4*)&b_lds[buf][cl][tpx >> 4][(tpx & 15) ^ cl][0] = v;
    };

    {
        uint4 v0 = stageLoad(0, spx);
        uint4 v1 = stageLoad(0, spx + 64);
        stageWrite(v0, 0, spx);
        stageWrite(v1, 0, spx + 64);
    }
    __syncthreads();

    for (int t = 0; t < 9; ++t) {
        int cur = t & 1;
        uint4 n0, n1;
        if (t < 8) {
            n0 = stageLoad(t + 1, spx);
            n1 = stageLoad(t + 1, spx + 64);
        }
        bf16x8 a00 = w1v[(size_t)(t * 32 + cs * 8 + 0 * 4 + lq) * 32 + 0 * 16 + l16];
        bf16x8 a01 = w1v[(size_t)(t * 32 + cs * 8 + 0 * 4 + lq) * 32 + 1 * 16 + l16];
        bf16x8 a10 = w1v[(size_t)(t * 32 + cs * 8 + 1 * 4 + lq) * 32 + 0 * 16 + l16];
        bf16x8 a11 = w1v[(size_t)(t * 32 + cs * 8 + 1 * 4 + lq) * 32 + 1 * 16 + l16];
        bf16x8 b0 = *(const bf16x8*)&b_lds[cur][0 * 4 + lq][wv][l16 ^ (0 * 4 + lq)][0];
        bf16x8 b1 = *(const bf16x8*)&b_lds[cur][1 * 4 + lq][wv][l16 ^ (1 * 4 + lq)][0];
        acc[0] = __builtin_amdgcn_mfma_f32_16x16x32_bf16(a00, b0, acc[0], 0, 0, 0);
        acc[1] = __builtin_amdgcn_mfma_f32_16x16x32_bf16(a01, b0, acc[1], 0, 0, 0);
        acc[0] = __builtin_amdgcn_mfma_f32_16x16x32_bf16(a10, b1, acc[0], 0, 0, 0);
        acc[1] = __builtin_amdgcn_mfma_f32_16x16x32_bf16(a11, b1, acc[1], 0, 0, 0);
        if (t < 8) {
            stageWrite(n0, cur ^ 1, spx);
            stageWrite(n1, cur ^ 1, spx + 64);
        }
        __syncthreads();
    }

    int prow = hg * 2 + (wv >> 2);
    int pcol = (wv & 3) * 16 + l16;
#pragma unroll
    for (int mf = 0; mf < 2; ++mf) {
#pragma unroll
        for (int r = 0; r < 4; ++r) {
            int o = mf * 16 + lq * 4 + r;
            if (o < 27) {
                atomicAdd(&P[((size_t)b * 27 + o) * HWSZ + prow * WW + pcol],
                          acc[mf][r]);
            }
        }
    }
}

// ---------------------------------------------------------------------------
// Kernel 3: deformable sampling + bf16 MFMA GEMM (R9/R13 k_deform8 structure,
// verified) with ONE change: lgkm-only barriers. In-flight register gathers
// now survive the barrier instead of being drained by __syncthreads'
// vmcnt(0) — the 2-chunk-ahead pipeline becomes real.
// Tile 256o x 64px, 512 thr, cs-split x2, grid 512, XCD-swizzled.
// ---------------------------------------------------------------------------
__global__ __launch_bounds__(512, 4) void k_deform14(const ushort* __restrict__ xT,
                                                     const float* __restrict__ P,
                                                     const float* __restrict__ b_off,
                                                     const ushort* __restrict__ w2F,
                                                     float* __restrict__ out) {
    int bid = blockIdx.x;
    int L = (bid & 7) * 64 + (bid >> 3);
    int cs = L & 1;
    int h  = (L >> 1) & 63;
    int b  = L >> 7;
    int tid = threadIdx.x;
    int lane = tid & 63;
    int wv   = tid >> 6;          // 0..7 -> o block = wv*32
    int l16  = lane & 15;
    int lq   = lane >> 4;
    int px   = tid >> 3;          // 0..63
    int cl   = tid & 7;           // 8-channel slot

    __shared__ ushort b_lds[2][8][4][16][8];   // [buf][kg][nt][p^kg][j] 16KB

    const char* xTc = (const char*)xT + (size_t)b * HWSZ * 512 + cs * 256 + cl * 16;
    const bf16x8* w2b = (const bf16x8*)w2F + (size_t)(cs * 16) * 256 + wv * 32 + l16;

    uint4* wdst0 = (uint4*)&b_lds[0][cl][px >> 4][(px & 15) ^ cl][0];
    uint4* wdst1 = (uint4*)&b_lds[1][cl][px >> 4][(px & 15) ^ cl][0];

    f32x4 acc[2][4];
#pragma unroll
    for (int mf = 0; mf < 2; ++mf)
#pragma unroll
        for (int nt = 0; nt < 4; ++nt) acc[mf][nt] = (f32x4){0.f, 0.f, 0.f, 0.f};

    const float* Pb = P + (size_t)b * 27 * HWSZ + h * WW + px;

    float pOy, pOx, pMr, bOy, bOx, bMr;
    float wgt[4];
    const char* aptr[4];

    auto loadP = [&](int k) {
        pOy = Pb[(size_t)(2 * k) * HWSZ];
        pOx = Pb[(size_t)(2 * k + 1) * HWSZ];
        pMr = Pb[(size_t)(18 + k) * HWSZ];
        bOy = b_off[2 * k];
        bOx = b_off[2 * k + 1];
        bMr = b_off[18 + k];
    };
    auto calcDesc = [&](int k) {
        float offy = pOy + bOy;
        float offx = pOx + bOx;
        float m = 1.0f / (1.0f + expf(-(pMr + bMr)));
        float sy = offy + (float)(h + k / 3 - 1);
        float sx = offx + (float)(px + k % 3 - 1);
        float y0f = floorf(sy), x0f = floorf(sx);
        float ty = sy - y0f, tx = sx - x0f;
        int y0 = (int)y0f, x0 = (int)x0f;
#pragma unroll
        for (int dy = 0; dy < 2; ++dy) {
#pragma unroll
            for (int dx = 0; dx < 2; ++dx) {
                int yi = y0 + dy, xi = x0 + dx;
                bool ok = (yi >= 0 && yi < HH && xi >= 0 && xi < WW);
                float wg = (dy ? ty : 1.0f - ty) * (dx ? tx : 1.0f - tx) * m;
                wgt[dy * 2 + dx]  = ok ? wg : 0.0f;
                aptr[dy * 2 + dx] = xTc + (size_t)(ok ? (yi * WW + xi) : 0) * 512;
            }
        }
    };

    // named pipeline slots (static indexing only — rule #20)
    uint4 gbA[4], gbB[4];
    float wgtA[4], wgtB[4];
    bf16x8 aA[2][2], aB[2][2];

    auto issueGatherTo = [&](uint4 (&gb)[4], float (&wg)[4], int off) {
#pragma unroll
        for (int c = 0; c < 4; ++c) gb[c] = *(const uint4*)(aptr[c] + off);
#pragma unroll
        for (int c = 0; c < 4; ++c) wg[c] = wgt[c];
    };
    auto combineFrom = [&](const uint4 (&g)[4], const float (&w)[4]) -> uint4 {
        uint4 r;
        {
            float lo = w[0]*blo(g[0].x) + w[1]*blo(g[1].x) + w[2]*blo(g[2].x) + w[3]*blo(g[3].x);
            float hi = w[0]*bhi(g[0].x) + w[1]*bhi(g[1].x) + w[2]*bhi(g[2].x) + w[3]*bhi(g[3].x);
            r.x = packbf(lo, hi);
        }
        {
            float lo = w[0]*blo(g[0].y) + w[1]*blo(g[1].y) + w[2]*blo(g[2].y) + w[3]*blo(g[3].y);
            float hi = w[0]*bhi(g[0].y) + w[1]*bhi(g[1].y) + w[2]*bhi(g[2].y) + w[3]*bhi(g[3].y);
            r.y = packbf(lo, hi);
        }
        {
            float lo = w[0]*blo(g[0].z) + w[1]*blo(g[1].z) + w[2]*blo(g[2].z) + w[3]*blo(g[3].z);
            float hi = w[0]*bhi(g[0].z) + w[1]*bhi(g[1].z) + w[2]*bhi(g[2].z) + w[3]*bhi(g[3].z);
            r.z = packbf(lo, hi);
        }
        {
            float lo = w[0]*blo(g[0].w) + w[1]*blo(g[1].w) + w[2]*blo(g[2].w) + w[3]*blo(g[3].w);
            float hi = w[0]*bhi(g[0].w) + w[1]*bhi(g[1].w) + w[2]*bhi(g[2].w) + w[3]*bhi(g[3].w);
            r.w = packbf(lo, hi);
        }
        return r;
    };
    auto loadATo = [&](bf16x8 (&a)[2][2], int t) {
        size_t base = ((size_t)((t >> 1) * 32 + (t & 1) * 8) + lq) * 256;
#pragma unroll
        for (int g = 0; g < 2; ++g)
#pragma unroll
            for (int mf = 0; mf < 2; ++mf)
                a[mf][g] = w2b[base + (size_t)g * 1024 + mf * 16];
    };

#define MFMA_BODY(BUF, AREG)                                                        \
    do {                                                                            \
        bf16x8 bfr[2][4];                                                           \
        _Pragma("unroll")                                                           \
        for (int g = 0; g < 2; ++g) {                                               \
            int kg = g * 4 + lq;                                                    \
            _Pragma("unroll")                                                       \
            for (int nt = 0; nt < 4; ++nt)                                          \
                bfr[g][nt] = *(const bf16x8*)&b_lds[BUF][kg][nt][l16 ^ kg][0];      \
        }                                                                           \
        _Pragma("unroll")                                                           \
        for (int g = 0; g < 2; ++g)                                                 \
            _Pragma("unroll")                                                       \
            for (int mf = 0; mf < 2; ++mf)                                          \
                _Pragma("unroll")                                                   \
                for (int nt = 0; nt < 4; ++nt)                                      \
                    acc[mf][nt] = __builtin_amdgcn_mfma_f32_16x16x32_bf16(          \
                        AREG[mf][g], bfr[g][nt], acc[mf][nt], 0, 0, 0);             \
    } while (0)

    // --- prologue: chunks 0 (->gbA->buf0) and 1 (->gbB), A chunk 0 ---
    loadP(0);
    calcDesc(0);
    issueGatherTo(gbA, wgtA, 0);
    issueGatherTo(gbB, wgtB, 128);
    loadP(1);
    loadATo(aA, 0);
    *wdst0 = combineFrom(gbA, wgtA);
    lgkm_sync();

    for (int tp = 0; tp < 9; ++tp) {
        // ---- even body: t = 2tp. reads buf0 / aA; combines gbB -> buf1 ----
        if (tp < 8) {
            calcDesc(tp + 1);                 // P loaded at previous odd body
            issueGatherTo(gbA, wgtA, 0);      // chunk 2tp+2 (k=tp+1, lo half)
        }
        loadATo(aB, 2 * tp + 1);
        MFMA_BODY(0, aA);
        *wdst1 = combineFrom(gbB, wgtB);      // chunk 2tp+1 -> buf1
        lgkm_sync();

        // ---- odd body: t = 2tp+1. reads buf1 / aB; combines gbA -> buf0 ----
        if (tp < 8) {
            issueGatherTo(gbB, wgtB, 128);    // chunk 2tp+3 (k=tp+1, hi half)
            if (tp < 7) loadP(tp + 2);
            loadATo(aA, 2 * tp + 2);
        }
        MFMA_BODY(1, aB);
        if (tp < 8) {
            *wdst0 = combineFrom(gbA, wgtA);  // chunk 2tp+2 -> buf0
        }
        lgkm_sync();
    }
#undef MFMA_BODY

    // epilogue: atomic accumulate (out prefilled with bias)
#pragma unroll
    for (int mf = 0; mf < 2; ++mf) {
#pragma unroll
        for (int nt = 0; nt < 4; ++nt) {
#pragma unroll
            for (int r = 0; r < 4; ++r) {
                int o = wv * 32 + mf * 16 + lq * 4 + r;
                atomicAdd(&out[((size_t)b * OCH + o) * HWSZ + h * WW + nt * 16 + l16],
                          acc[mf][nt][r]);
            }
        }
    }
}

// ---------------------------------------------------------------------------
extern "C" void kernel_launch(void* const* d_in, const int* in_sizes, int n_in,
                              void* d_out, int out_size, void* d_ws, size_t ws_size,
                              hipStream_t stream) {
    const float* x     = (const float*)d_in[0];
    const float* w_off = (const float*)d_in[1];
    const float* b_off = (const float*)d_in[2];
    const float* w_def = (const float*)d_in[3];
    const float* b_def = (const float*)d_in[4];
    float* out = (float*)d_out;

    float*  P   = (float*)d_ws;                            // 442368 f32
    ushort* w1F = (ushort*)(P + (size_t)BB * 27 * HWSZ);   // 73728 bf16
    ushort* w2F = w1F + 73728;                             // 589824 bf16
    ushort* xT  = w2F + 589824;                            // 4.19M bf16

    hipLaunchKernelGGL(k_prep, dim3(7376), dim3(256), 0, stream,
                       x, w_off, w_def, b_def, xT, w1F, w2F, P, out);
    hipLaunchKernelGGL(k_pred4, dim3(512), dim3(512), 0, stream, xT, w1F, P);
    hipLaunchKernelGGL(k_deform14, dim3(512), dim3(512), 0, stream, xT, P, b_off, w2F, out);
}

// Round 16
// 76.582 us; speedup vs baseline: 1.2316x; 1.0983x over previous
//
#include <hip/hip_runtime.h>

#define BB 4
#define CCH 256
#define OCH 256
#define HH 64
#define WW 64
#define HWSZ 4096

typedef __bf16 bf16_t;
typedef bf16_t bf16x8 __attribute__((ext_vector_type(8)));
typedef bf16_t bf16x2_t __attribute__((ext_vector_type(2)));
typedef float f32x4 __attribute__((ext_vector_type(4)));

// RNE f32x2 -> packed bf16 (compiler emits v_cvt_pk_bf16_f32)
__device__ __forceinline__ unsigned int packbf(float a, float b) {
    bf16x2_t p;
    p.x = (__bf16)a;
    p.y = (__bf16)b;
    return __builtin_bit_cast(unsigned int, p);
}
__device__ __forceinline__ float blo(unsigned int u) { return __uint_as_float(u << 16); }
__device__ __forceinline__ float bhi(unsigned int u) { return __uint_as_float(u & 0xFFFF0000u); }

// raw barrier used by k_pred4 path (verified R13)
__device__ __forceinline__ void block_sync() {
    asm volatile("s_waitcnt lgkmcnt(0)" ::: "memory");
    __builtin_amdgcn_s_barrier();
    __builtin_amdgcn_sched_barrier(0);
}

// ---------------------------------------------------------------------------
// Kernel prep: blocks [0,256): x -> xT bf16 transpose.
// blocks [256,...): w1F repack | w2F repack | P zero.  (out-prefill REMOVED —
// deform now px-split with direct stores, saving 67 MB of HBM writes.)
// ---------------------------------------------------------------------------
__global__ __launch_bounds__(256) void k_prep(const float* __restrict__ x,
                                              const float* __restrict__ w_off,
                                              const float* __restrict__ w_def,
                                              ushort* __restrict__ xT,
                                              ushort* __restrict__ w1F,
                                              ushort* __restrict__ w2F,
                                              float* __restrict__ P) {
    int bid = blockIdx.x;
    if (bid < 256) {
        int b = bid >> 6;
        int h = bid & 63;
        int tid = threadIdx.x;
        int wv = tid >> 6;
        int lane = tid & 63;

        __shared__ unsigned int buf[64][130];

        const float* xp = x + ((size_t)b * CCH + wv * 64) * HWSZ + h * WW + lane;
#pragma unroll 8
        for (int i = 0; i < 32; ++i) {
            float a = xp[(size_t)(2 * i) * HWSZ];
            float c = xp[(size_t)(2 * i + 1) * HWSZ];
            buf[lane][wv * 32 + i] = packbf(a, c);
        }
        __syncthreads();

        ushort* dst = xT + ((size_t)(b * 64 + h) * 64) * 256;
#pragma unroll
        for (int r = 0; r < 16; ++r) {
            int idx = tid + r * 256;
            int w = idx >> 6;
            int q = idx & 63;
            uint2 v = *(const uint2*)&buf[w][2 * q];
            *(uint2*)(dst + (size_t)w * 256 + q * 4) = v;
        }
        return;
    }

    int i = (bid - 256) * 256 + threadIdx.x;
    if (i < 73728) {
        int j = i & 7;
        int o = (i >> 3) & 31;
        int cSub = (i >> 8) & 31;
        int k = i >> 13;
        float v = 0.0f;
        if (o < 27) v = w_off[((size_t)o * CCH + cSub * 8 + j) * 9 + k];
        w1F[i] = (ushort)(packbf(v, 0.f) & 0xFFFFu);
        return;
    }
    i -= 73728;
    if (i < 589824) {
        int j = i & 7;
        int o = (i >> 3) & 255;
        int cg = (i >> 11) & 31;
        int k = i >> 16;
        float v = w_def[(size_t)o * 2304 + (cg * 8 + j) * 9 + k];
        w2F[i] = (ushort)(packbf(v, 0.f) & 0xFFFFu);
        return;
    }
    i -= 589824;
    if (i < 110592) {
        ((float4*)P)[i] = make_float4(0.f, 0.f, 0.f, 0.f);
    }
}

// ---------------------------------------------------------------------------
// Kernel 2 (verified R13): pred conv via MFMA, 32o x 128px tiles, 9 chunks.
// ---------------------------------------------------------------------------
__global__ __launch_bounds__(512) void k_pred4(const ushort* __restrict__ xT,
                                               const ushort* __restrict__ w1F,
                                               float* __restrict__ P) {
    int bid = blockIdx.x;
    int L = (bid & 7) * 64 + (bid >> 3);
    int cs = L & 3;
    int hg = (L >> 2) & 31;
    int b  = L >> 7;
    int tid = threadIdx.x;
    int lane = tid & 63;
    int wv   = tid >> 6;
    int l16  = lane & 15;
    int lq   = lane >> 4;
    int spx  = tid >> 3;
    int cl   = tid & 7;

    __shared__ ushort b_lds[2][8][8][16][8];   // 32KB

    const ushort* xTb = xT + (size_t)b * HWSZ * 256 + cs * 64 + cl * 8;
    const bf16x8* w1v = (const bf16x8*)w1F;

    f32x4 acc[2];
    acc[0] = (f32x4){0.f, 0.f, 0.f, 0.f};
    acc[1] = (f32x4){0.f, 0.f, 0.f, 0.f};

    auto stageLoad = [&](int k, int tpx) -> uint4 {
        int row = hg * 2 + (tpx >> 6);
        int col = tpx & 63;
        int ys = row + k / 3 - 1;
        int xs = col + k % 3 - 1;
        bool ok = (ys >= 0 && ys < HH && xs >= 0 && xs < WW);
        uint4 v = make_uint4(0u, 0u, 0u, 0u);
        if (ok) v = *(const uint4*)(xTb + (size_t)(ys * WW + xs) * 256);
        return v;
    };
    auto stageWrite = [&](uint4 v, int buf, int tpx) {
        *(uint4*)&b_lds[buf][cl][tpx >> 4][(tpx & 15) ^ cl][0] = v;
    };

    {
        uint4 v0 = stageLoad(0, spx);
        uint4 v1 = stageLoad(0, spx + 64);
        stageWrite(v0, 0, spx);
        stageWrite(v1, 0, spx + 64);
    }
    __syncthreads();

    for (int t = 0; t < 9; ++t) {
        int cur = t & 1;
        uint4 n0, n1;
        if (t < 8) {
            n0 = stageLoad(t + 1, spx);
            n1 = stageLoad(t + 1, spx + 64);
        }
        bf16x8 a00 = w1v[(size_t)(t * 32 + cs * 8 + 0 * 4 + lq) * 32 + 0 * 16 + l16];
        bf16x8 a01 = w1v[(size_t)(t * 32 + cs * 8 + 0 * 4 + lq) * 32 + 1 * 16 + l16];
        bf16x8 a10 = w1v[(size_t)(t * 32 + cs * 8 + 1 * 4 + lq) * 32 + 0 * 16 + l16];
        bf16x8 a11 = w1v[(size_t)(t * 32 + cs * 8 + 1 * 4 + lq) * 32 + 1 * 16 + l16];
        bf16x8 b0 = *(const bf16x8*)&b_lds[cur][0 * 4 + lq][wv][l16 ^ (0 * 4 + lq)][0];
        bf16x8 b1 = *(const bf16x8*)&b_lds[cur][1 * 4 + lq][wv][l16 ^ (1 * 4 + lq)][0];
        acc[0] = __builtin_amdgcn_mfma_f32_16x16x32_bf16(a00, b0, acc[0], 0, 0, 0);
        acc[1] = __builtin_amdgcn_mfma_f32_16x16x32_bf16(a01, b0, acc[1], 0, 0, 0);
        acc[0] = __builtin_amdgcn_mfma_f32_16x16x32_bf16(a10, b1, acc[0], 0, 0, 0);
        acc[1] = __builtin_amdgcn_mfma_f32_16x16x32_bf16(a11, b1, acc[1], 0, 0, 0);
        if (t < 8) {
            stageWrite(n0, cur ^ 1, spx);
            stageWrite(n1, cur ^ 1, spx + 64);
        }
        __syncthreads();
    }

    int prow = hg * 2 + (wv >> 2);
    int pcol = (wv & 3) * 16 + l16;
#pragma unroll
    for (int mf = 0; mf < 2; ++mf) {
#pragma unroll
        for (int r = 0; r < 4; ++r) {
            int o = mf * 16 + lq * 4 + r;
            if (o < 27) {
                atomicAdd(&P[((size_t)b * 27 + o) * HWSZ + prow * WW + pcol],
                          acc[mf][r]);
            }
        }
    }
}

// ---------------------------------------------------------------------------
// Kernel 3: deformable sampling + bf16 MFMA GEMM — PX-SPLIT, direct stores.
// Tile 256o x 32px, full K=2304 per block -> no atomics, no out-prefill.
// Chunk = tap x 128ch -> 18 chunks / 9 pairs: IDENTICAL loop structure,
// cadence, and slot layout to verified R9/R13 k_deform8 (desc once per pair,
// gather offsets alternate 0/256, gbA/gbB + wgt snapshots, aA/aB ping-pong,
// __syncthreads). grid = 512, XCD-swizzled (one b x 32 h-rows per XCD).
// Staging: thread (pxs = tid>>4, cl = tid&15) stages kg row cl of 16.
// ---------------------------------------------------------------------------
__global__ __launch_bounds__(512, 4) void k_deform15(const ushort* __restrict__ xT,
                                                     const float* __restrict__ P,
                                                     const float* __restrict__ b_off,
                                                     const ushort* __restrict__ w2F,
                                                     const float* __restrict__ b_def,
                                                     float* __restrict__ out) {
    int bid = blockIdx.x;
    int L = (bid & 7) * 64 + (bid >> 3);
    int ph = L & 1;               // px half
    int h  = (L >> 1) & 63;
    int b  = L >> 7;
    int px0 = ph * 32;
    int tid = threadIdx.x;
    int lane = tid & 63;
    int wv   = tid >> 6;          // 0..7 -> o block = wv*32
    int l16  = lane & 15;
    int lq   = lane >> 4;
    int pxs  = tid >> 4;          // 0..31 staging pixel
    int cl   = tid & 15;          // kg row slot (8 ch each, 16 rows/chunk)

    __shared__ ushort b_lds[2][16][2][16][8];  // [buf][kg][nt][p^kg][j] 16KB

    const char* xTc = (const char*)xT + (size_t)b * HWSZ * 512 + cl * 16;
    const bf16x8* w2b = (const bf16x8*)w2F + wv * 32 + l16;

    uint4* wdst0 = (uint4*)&b_lds[0][cl][pxs >> 4][(pxs & 15) ^ cl][0];
    uint4* wdst1 = (uint4*)&b_lds[1][cl][pxs >> 4][(pxs & 15) ^ cl][0];

    f32x4 acc[2][2];
#pragma unroll
    for (int mf = 0; mf < 2; ++mf)
#pragma unroll
        for (int nt = 0; nt < 2; ++nt) acc[mf][nt] = (f32x4){0.f, 0.f, 0.f, 0.f};

    const float* Pb = P + (size_t)b * 27 * HWSZ + h * WW + px0 + pxs;

    float pOy, pOx, pMr, bOy, bOx, bMr;
    float wgt[4];
    const char* aptr[4];

    auto loadP = [&](int k) {
        pOy = Pb[(size_t)(2 * k) * HWSZ];
        pOx = Pb[(size_t)(2 * k + 1) * HWSZ];
        pMr = Pb[(size_t)(18 + k) * HWSZ];
        bOy = b_off[2 * k];
        bOx = b_off[2 * k + 1];
        bMr = b_off[18 + k];
    };
    auto calcDesc = [&](int k) {
        float offy = pOy + bOy;
        float offx = pOx + bOx;
        float m = 1.0f / (1.0f + expf(-(pMr + bMr)));
        float sy = offy + (float)(h + k / 3 - 1);
        float sx = offx + (float)(px0 + pxs + k % 3 - 1);
        float y0f = floorf(sy), x0f = floorf(sx);
        float ty = sy - y0f, tx = sx - x0f;
        int y0 = (int)y0f, x0 = (int)x0f;
#pragma unroll
        for (int dy = 0; dy < 2; ++dy) {
#pragma unroll
            for (int dx = 0; dx < 2; ++dx) {
                int yi = y0 + dy, xi = x0 + dx;
                bool ok = (yi >= 0 && yi < HH && xi >= 0 && xi < WW);
                float wg = (dy ? ty : 1.0f - ty) * (dx ? tx : 1.0f - tx) * m;
                wgt[dy * 2 + dx]  = ok ? wg : 0.0f;
                aptr[dy * 2 + dx] = xTc + (size_t)(ok ? (yi * WW + xi) : 0) * 512;
            }
        }
    };

    // named pipeline slots (static indexing only — rule #20)
    uint4 gbA[4], gbB[4];
    float wgtA[4], wgtB[4];
    bf16x8 aA[2][4], aB[2][4];

    auto issueGatherTo = [&](uint4 (&gb)[4], float (&wg)[4], int off) {
#pragma unroll
        for (int c = 0; c < 4; ++c) gb[c] = *(const uint4*)(aptr[c] + off);
#pragma unroll
        for (int c = 0; c < 4; ++c) wg[c] = wgt[c];
    };
    auto combineFrom = [&](const uint4 (&g)[4], const float (&w)[4]) -> uint4 {
        uint4 r;
        {
            float lo = w[0]*blo(g[0].x) + w[1]*blo(g[1].x) + w[2]*blo(g[2].x) + w[3]*blo(g[3].x);
            float hi = w[0]*bhi(g[0].x) + w[1]*bhi(g[1].x) + w[2]*bhi(g[2].x) + w[3]*bhi(g[3].x);
            r.x = packbf(lo, hi);
        }
        {
            float lo = w[0]*blo(g[0].y) + w[1]*blo(g[1].y) + w[2]*blo(g[2].y) + w[3]*blo(g[3].y);
            float hi = w[0]*bhi(g[0].y) + w[1]*bhi(g[1].y) + w[2]*bhi(g[2].y) + w[3]*bhi(g[3].y);
            r.y = packbf(lo, hi);
        }
        {
            float lo = w[0]*blo(g[0].z) + w[1]*blo(g[1].z) + w[2]*blo(g[2].z) + w[3]*blo(g[3].z);
            float hi = w[0]*bhi(g[0].z) + w[1]*bhi(g[1].z) + w[2]*bhi(g[2].z) + w[3]*bhi(g[3].z);
            r.z = packbf(lo, hi);
        }
        {
            float lo = w[0]*blo(g[0].w) + w[1]*blo(g[1].w) + w[2]*blo(g[2].w) + w[3]*blo(g[3].w);
            float hi = w[0]*bhi(g[0].w) + w[1]*bhi(g[1].w) + w[2]*bhi(g[2].w) + w[3]*bhi(g[3].w);
            r.w = packbf(lo, hi);
        }
        return r;
    };
    // chunk t: tap = t>>1, chalf = t&1 -> w2F rows tap*32 + chalf*16 + g*4 + lq
    auto loadATo = [&](bf16x8 (&a)[2][4], int t) {
        size_t base = ((size_t)((t >> 1) * 32 + (t & 1) * 16) + lq) * 256;
#pragma unroll
        for (int g = 0; g < 4; ++g)
#pragma unroll
            for (int mf = 0; mf < 2; ++mf)
                a[mf][g] = w2b[base + (size_t)g * 1024 + mf * 16];
    };

#define MFMA_BODY(BUF, AREG)                                                        \
    do {                                                                            \
        bf16x8 bfr[4][2];                                                           \
        _Pragma("unroll")                                                           \
        for (int g = 0; g < 4; ++g) {                                               \
            int kg = g * 4 + lq;                                                    \
            _Pragma("unroll")                                                       \
            for (int nt = 0; nt < 2; ++nt)                                          \
                bfr[g][nt] = *(const bf16x8*)&b_lds[BUF][kg][nt][l16 ^ kg][0];      \
        }                                                                           \
        _Pragma("unroll")                                                           \
        for (int g = 0; g < 4; ++g)                                                 \
            _Pragma("unroll")                                                       \
            for (int mf = 0; mf < 2; ++mf)                                          \
                _Pragma("unroll")                                                   \
                for (int nt = 0; nt < 2; ++nt)                                      \
                    acc[mf][nt] = __builtin_amdgcn_mfma_f32_16x16x32_bf16(          \
                        AREG[mf][g], bfr[g][nt], acc[mf][nt], 0, 0, 0);             \
    } while (0)

    // --- prologue: chunks 0 (->gbA->buf0) and 1 (->gbB), A chunk 0 ---
    loadP(0);
    calcDesc(0);
    issueGatherTo(gbA, wgtA, 0);
    issueGatherTo(gbB, wgtB, 256);
    loadP(1);
    loadATo(aA, 0);
    *wdst0 = combineFrom(gbA, wgtA);
    __syncthreads();

    for (int tp = 0; tp < 9; ++tp) {
        // ---- even body: t = 2tp. reads buf0 / aA; combines gbB -> buf1 ----
        if (tp < 8) {
            calcDesc(tp + 1);                 // P loaded at previous odd body
            issueGatherTo(gbA, wgtA, 0);      // chunk 2tp+2 (tap tp+1, lo half)
        }
        loadATo(aB, 2 * tp + 1);
        MFMA_BODY(0, aA);
        *wdst1 = combineFrom(gbB, wgtB);      // chunk 2tp+1 -> buf1
        __syncthreads();

        // ---- odd body: t = 2tp+1. reads buf1 / aB; combines gbA -> buf0 ----
        if (tp < 8) {
            issueGatherTo(gbB, wgtB, 256);    // chunk 2tp+3 (tap tp+1, hi half)
            if (tp < 7) loadP(tp + 2);
            loadATo(aA, 2 * tp + 2);
        }
        MFMA_BODY(1, aB);
        if (tp < 8) {
            *wdst0 = combineFrom(gbA, wgtA);  // chunk 2tp+2 -> buf0
        }
        __syncthreads();
    }
#undef MFMA_BODY

    // epilogue: direct store (each output owned by exactly one block)
#pragma unroll
    for (int mf = 0; mf < 2; ++mf) {
#pragma unroll
        for (int nt = 0; nt < 2; ++nt) {
#pragma unroll
            for (int r = 0; r < 4; ++r) {
                int o = wv * 32 + mf * 16 + lq * 4 + r;
                out[((size_t)b * OCH + o) * HWSZ + h * WW + px0 + nt * 16 + l16] =
                    acc[mf][nt][r] + b_def[o];
            }
        }
    }
}

// ---------------------------------------------------------------------------
extern "C" void kernel_launch(void* const* d_in, const int* in_sizes, int n_in,
                              void* d_out, int out_size, void* d_ws, size_t ws_size,
                              hipStream_t stream) {
    const float* x     = (const float*)d_in[0];
    const float* w_off = (const float*)d_in[1];
    const float* b_off = (const float*)d_in[2];
    const float* w_def = (const float*)d_in[3];
    const float* b_def = (const float*)d_in[4];
    float* out = (float*)d_out;

    float*  P   = (float*)d_ws;                            // 442368 f32
    ushort* w1F = (ushort*)(P + (size_t)BB * 27 * HWSZ);   // 73728 bf16
    ushort* w2F = w1F + 73728;                             // 589824 bf16
    ushort* xT  = w2F + 589824;                            // 4.19M bf16

    hipLaunchKernelGGL(k_prep, dim3(3280), dim3(256), 0, stream,
                       x, w_off, w_def, xT, w1F, w2F, P);
    hipLaunchKernelGGL(k_pred4, dim3(512), dim3(512), 0, stream, xT, w1F, P);
    hipLaunchKernelGGL(k_deform15, dim3(512), dim3(512), 0, stream,
                       xT, P, b_off, w2F, b_def, out);
}